// Round 7
// baseline (300.456 us; speedup 1.0000x reference)
//
#include <hip/hip_runtime.h>
#include <hip/hip_bf16.h>
#include <math.h>

// Problem constants (fixed by setup_inputs)
#define B_DOC 32
#define S_MAX 40
#define T_K 64
#define N_DIM 512
#define B_SENT (B_DOC * S_MAX)      // 1280
#define MAXDOC (S_MAX * T_K)        // 2560
#define KCHUNK 4                    // word fea GEMV k-split

__device__ __forceinline__ float fast_tanh(float x) {
    float e = __expf(2.0f * x);
    return 1.0f - 2.0f * __builtin_amdgcn_rcpf(e + 1.0f);
}

// ============ LAUNCH 1: word-fea (0..127) | prep (128) | sent attn (129..160)
__global__ __launch_bounds__(256) void stage1_kernel(
        const int* __restrict__ seq_lens2, const int* __restrict__ sent_lens,
        const float* __restrict__ s_t_hat, const float* __restrict__ sent_s_t_hat,
        const float* __restrict__ Wd, const float* __restrict__ bd,
        const float* __restrict__ Wsd, const float* __restrict__ bsd,
        const float* __restrict__ sef, const float* __restrict__ sv_w,
        const float* __restrict__ mask,
        float* __restrict__ fea_part, float* __restrict__ o_sent,
        int* __restrict__ doc_ids, int* __restrict__ sent_local,
        int* __restrict__ doc_word_off, int* __restrict__ sent_start_g,
        int* __restrict__ doc_words_total, int* __restrict__ cnt) {
    int tid = threadIdx.x;
    int blk = blockIdx.x;
    if (blk < 128) {
        // ---- word-level fea: k-split GEMV partials ----
        int c = blk & (KCHUNK - 1);
        int b = blk >> 2;
        const int KC = N_DIM / KCHUNK;   // 128
        const float* x = s_t_hat + b * N_DIM + c * KC;
        const float* W = Wd + (size_t)c * KC * N_DIM;
        float* out = fea_part + ((size_t)b * KCHUNK + c) * N_DIM;
        __shared__ float xs[128];
        if (tid < KC) xs[tid] = x[tid];
        __syncthreads();
        float a0 = 0.f, a1 = 0.f;
        if (c == 0) { a0 = bd[tid]; a1 = bd[tid + 256]; }
        #pragma unroll 8
        for (int k = 0; k < KC; ++k) {
            float xv = xs[k];
            a0 = fmaf(xv, W[k * N_DIM + tid], a0);
            a1 = fmaf(xv, W[k * N_DIM + tid + 256], a1);
        }
        out[tid] = a0;
        out[tid + 256] = a1;
    } else if (blk == 128) {
        // ---- prep: fully parallel scans + zero doc counters ----
        __shared__ int ss[B_DOC + 1];
        __shared__ int wc[B_SENT + 1];
        __shared__ int wsum[4];
        int lane = tid & 63, w = tid >> 6;
        if (tid < B_DOC) cnt[tid] = 0;

        int ls[5];
        #pragma unroll
        for (int k = 0; k < 5; ++k) ls[k] = seq_lens2[tid * 5 + k];
        int sum = ls[0] + ls[1] + ls[2] + ls[3] + ls[4];

        int scan = sum;
        #pragma unroll
        for (int off = 1; off < 64; off <<= 1) {
            int v = __shfl_up(scan, off, 64);
            if (lane >= off) scan += v;
        }
        if (lane == 63) wsum[w] = scan;

        if (w == 0) {
            int sl = (lane < B_DOC) ? sent_lens[lane] : 0;
            int sc2 = sl;
            #pragma unroll
            for (int off = 1; off < 64; off <<= 1) {
                int v = __shfl_up(sc2, off, 64);
                if (lane >= off) sc2 += v;
            }
            if (lane < B_DOC) ss[lane + 1] = sc2;
            if (lane == 0) ss[0] = 0;
        }
        __syncthreads();

        int wbase = 0;
        for (int i = 0; i < w; ++i) wbase += wsum[i];
        int excl = wbase + scan - sum;
        #pragma unroll
        for (int k = 0; k < 5; ++k) { wc[tid * 5 + k] = excl; excl += ls[k]; }
        if (tid == 255) wc[B_SENT] = excl;
        __syncthreads();

        if (tid <= B_DOC) sent_start_g[tid] = ss[tid];
        if (tid < B_DOC) doc_words_total[tid] = wc[ss[tid + 1]] - wc[ss[tid]];

        for (int i = tid; i < B_SENT; i += 256) {
            int lo = 0, hi = B_DOC - 1;
            while (lo < hi) { int mid = (lo + hi + 1) >> 1; if (ss[mid] <= i) lo = mid; else hi = mid - 1; }
            doc_ids[i] = lo;
            sent_local[i] = i - ss[lo];
            doc_word_off[i] = wc[i] - wc[ss[lo]];
        }
    } else {
        // ---- sentence-level attention, one doc per block ----
        int doc = blk - 129;
        __shared__ __align__(16) float xs[N_DIM];
        __shared__ __align__(16) float df[N_DIM];
        __shared__ __align__(16) float vw[N_DIM];
        __shared__ float sc[S_MAX];
        xs[tid] = sent_s_t_hat[doc * N_DIM + tid];
        xs[tid + 256] = sent_s_t_hat[doc * N_DIM + tid + 256];
        vw[tid] = sv_w[tid];
        vw[tid + 256] = sv_w[tid + 256];
        __syncthreads();
        // full 512-k GEMV: sent_dec_fea = xs @ Wsd + bsd
        float a0 = bsd[tid], a1 = bsd[tid + 256];
        #pragma unroll 8
        for (int k = 0; k < N_DIM; ++k) {
            float xv = xs[k];
            a0 = fmaf(xv, Wsd[k * N_DIM + tid], a0);
            a1 = fmaf(xv, Wsd[k * N_DIM + tid + 256], a1);
        }
        df[tid] = a0;
        df[tid + 256] = a1;
        __syncthreads();
        // 40 sentence scores: 8 groups x 32 lanes, 16 dims/lane
        int g = tid >> 5, sub = tid & 31;
        const float4* df4 = (const float4*)df;
        const float4* vw4 = (const float4*)vw;
        for (int r = g; r < S_MAX; r += 8) {
            const float4* row = (const float4*)(sef + ((size_t)doc * S_MAX + r) * N_DIM);
            float acc = 0.0f;
            #pragma unroll
            for (int k = 0; k < 4; ++k) {
                int j = sub + 32 * k;
                float4 e = row[j];
                float4 d = df4[j];
                float4 v = vw4[j];
                acc = fmaf(v.x, fast_tanh(e.x + d.x), acc);
                acc = fmaf(v.y, fast_tanh(e.y + d.y), acc);
                acc = fmaf(v.z, fast_tanh(e.z + d.z), acc);
                acc = fmaf(v.w, fast_tanh(e.w + d.w), acc);
            }
            #pragma unroll
            for (int off = 16; off >= 1; off >>= 1) acc += __shfl_xor(acc, off, 32);
            if (sub == 0) sc[r] = acc;
        }
        __syncthreads();
        // masked softmax over 40 (wave 0)
        if (tid < 64) {
            bool valid = tid < S_MAX;
            float x = valid ? sc[tid] : -INFINITY;
            float m = x;
            #pragma unroll
            for (int off = 32; off >= 1; off >>= 1) m = fmaxf(m, __shfl_xor(m, off, 64));
            float mk = valid ? mask[doc * S_MAX + tid] : 0.0f;
            float e = valid ? __expf(x - m) * mk : 0.0f;
            float ssum = e;
            #pragma unroll
            for (int off = 32; off >= 1; off >>= 1) ssum += __shfl_xor(ssum, off, 64);
            if (valid) o_sent[doc * S_MAX + tid] = e / ssum;
        }
    }
}

// ============ LAUNCH 2: fused scores+softmax+context + folded c_t reduction =
// 256 threads = 4 waves. Wave w, iteration i handles words t=8i+2w (half 0,
// lanes 0-31) and t+1 (half 1, lanes 32-63); 16 dims/lane. exp without max
// subtraction (|score| bounded; softmax ratio identical). Last block per doc
// (device-scope atomic counter) sums part rows in fixed order -> c_t.
__global__ __launch_bounds__(256, 4) void fused_kernel(
        const float* __restrict__ ef, const float* __restrict__ eo,
        const float* __restrict__ fea_part, const float* __restrict__ v_w,
        const float* __restrict__ sent_attn, const int* __restrict__ seq_lens2,
        const int* __restrict__ doc_ids, const int* __restrict__ sent_local,
        const int* __restrict__ doc_word_off, const int* __restrict__ sent_start,
        const int* __restrict__ doc_words_total, const int* __restrict__ mdl,
        const float* __restrict__ cov_in,
        float* __restrict__ part, float* __restrict__ out_attn,
        float* __restrict__ out_cov, float* __restrict__ c_t,
        int* __restrict__ cnt) {
    int s = blockIdx.x;
    int tid = threadIdx.x;
    int w = tid >> 6, lane = tid & 63;
    int h = lane >> 5, sub = lane & 31;
    __shared__ float sc[T_K];
    __shared__ float wl[4];
    __shared__ __align__(16) float4 red[4][128];
    __shared__ int isLast;

    int doc = doc_ids[s];
    int len = seq_lens2[s];
    int maxdoc = mdl[0];

    // dec_fea (sum of 4 k-chunks) and v_w into registers at cols sub+32k
    const float4* fp4 = (const float4*)(fea_part + (size_t)doc * KCHUNK * N_DIM);
    const float4* vw4 = (const float4*)v_w;
    float4 d[4], v[4];
    #pragma unroll
    for (int k = 0; k < 4; ++k) {
        int j = sub + 32 * k;
        float4 a = fp4[j], b = fp4[128 + j], c = fp4[256 + j], e = fp4[384 + j];
        d[k].x = a.x + b.x + c.x + e.x;
        d[k].y = a.y + b.y + c.y + e.y;
        d[k].z = a.z + b.z + c.z + e.z;
        d[k].w = a.w + b.w + c.w + e.w;
        v[k] = vw4[j];
    }

    // coverage passthrough
    if (tid < T_K) out_cov[s * T_K + tid] = cov_in[s * T_K + tid];

    const float4* ef4 = (const float4*)ef + (size_t)s * T_K * 128;
    const float4* eo4 = (const float4*)eo + (size_t)s * T_K * 128;

    float l_w = 0.0f;
    float4 O[4];
    #pragma unroll
    for (int k = 0; k < 4; ++k) O[k] = (float4){0.f, 0.f, 0.f, 0.f};

    int t = 2 * w;
    float4 ea[4];
    {   // first-iteration ef prefetch (row t+h < len always: len >= 32)
        int row = t + h;
        #pragma unroll
        for (int k = 0; k < 4; ++k) ea[k] = ef4[row * 128 + sub + 32 * k];
    }
    for (; t < len; t += 8) {
        int row = t + h;
        float4 p4[4];
        #pragma unroll
        for (int k = 0; k < 4; ++k) p4[k] = eo4[row * 128 + sub + 32 * k];
        float4 eb[4];
        int tn = t + 8;
        if (tn < len) {
            int rown = tn + h;
            #pragma unroll
            for (int k = 0; k < 4; ++k) eb[k] = ef4[rown * 128 + sub + 32 * k];
        }
        float a0, a1, a2, a3;
        a0  = v[0].x * fast_tanh(ea[0].x + d[0].x);
        a1  = v[1].x * fast_tanh(ea[1].x + d[1].x);
        a2  = v[2].x * fast_tanh(ea[2].x + d[2].x);
        a3  = v[3].x * fast_tanh(ea[3].x + d[3].x);
        a0 = fmaf(v[0].y, fast_tanh(ea[0].y + d[0].y), a0);
        a1 = fmaf(v[1].y, fast_tanh(ea[1].y + d[1].y), a1);
        a2 = fmaf(v[2].y, fast_tanh(ea[2].y + d[2].y), a2);
        a3 = fmaf(v[3].y, fast_tanh(ea[3].y + d[3].y), a3);
        a0 = fmaf(v[0].z, fast_tanh(ea[0].z + d[0].z), a0);
        a1 = fmaf(v[1].z, fast_tanh(ea[1].z + d[1].z), a1);
        a2 = fmaf(v[2].z, fast_tanh(ea[2].z + d[2].z), a2);
        a3 = fmaf(v[3].z, fast_tanh(ea[3].z + d[3].z), a3);
        a0 = fmaf(v[0].w, fast_tanh(ea[0].w + d[0].w), a0);
        a1 = fmaf(v[1].w, fast_tanh(ea[1].w + d[1].w), a1);
        a2 = fmaf(v[2].w, fast_tanh(ea[2].w + d[2].w), a2);
        a3 = fmaf(v[3].w, fast_tanh(ea[3].w + d[3].w), a3);
        float acc = (a0 + a1) + (a2 + a3);
        #pragma unroll
        for (int off = 16; off >= 1; off >>= 1) acc += __shfl_xor(acc, off, 64);
        bool valid = (t + h) < len;
        if (sub == 0 && valid) sc[t + h] = acc;
        float p = valid ? __expf(acc) : 0.0f;
        l_w += p;
        #pragma unroll
        for (int k = 0; k < 4; ++k) {
            O[k].x = fmaf(p, p4[k].x, O[k].x);
            O[k].y = fmaf(p, p4[k].y, O[k].y);
            O[k].z = fmaf(p, p4[k].z, O[k].z);
            O[k].w = fmaf(p, p4[k].w, O[k].w);
        }
        #pragma unroll
        for (int k = 0; k < 4; ++k) ea[k] = eb[k];
    }

    // combine halves within wave
    l_w += __shfl_xor(l_w, 32, 64);
    #pragma unroll
    for (int k = 0; k < 4; ++k) {
        O[k].x += __shfl_xor(O[k].x, 32, 64);
        O[k].y += __shfl_xor(O[k].y, 32, 64);
        O[k].z += __shfl_xor(O[k].z, 32, 64);
        O[k].w += __shfl_xor(O[k].w, 32, 64);
    }
    if (lane == 0) wl[w] = l_w;
    if (h == 0) {
        #pragma unroll
        for (int k = 0; k < 4; ++k) red[w][sub + 32 * k] = O[k];
    }
    __syncthreads();

    float l = (wl[0] + wl[1]) + (wl[2] + wl[3]);
    float sa = sent_attn[doc * S_MAX + sent_local[s]];
    float inv = sa / l;
    if (tid < 128) {
        float4 a = red[0][tid], b = red[1][tid], c = red[2][tid], e = red[3][tid];
        float4 r = {(a.x + b.x + c.x + e.x) * inv, (a.y + b.y + c.y + e.y) * inv,
                    (a.z + b.z + c.z + e.z) * inv, (a.w + b.w + c.w + e.w) * inv};
        ((float4*)(part + (size_t)s * N_DIM))[tid] = r;
    }
    // mult_attn scatter into attn_dist_sw
    if (tid < T_K && tid < len) {
        float mu = sa * __expf(sc[tid]) / l;
        out_attn[(size_t)doc * maxdoc + doc_word_off[s] + tid] = mu;
    }
    // tail zeroing: last sentence of each doc zeroes [doc_words, maxdoc)
    int st = sent_start[doc], en = sent_start[doc + 1];
    if (s + 1 == en) {
        int dwt = doc_words_total[doc];
        for (int i = dwt + tid; i < maxdoc; i += 256)
            out_attn[(size_t)doc * maxdoc + i] = 0.0f;
    }

    // ---- folded deterministic c_t reduction: last block of doc sums parts --
    __threadfence();                      // release part[s] device-wide
    if (tid == 0) {
        int old = atomicAdd(&cnt[doc], 1);
        isLast = (old == (en - st) - 1);
    }
    __syncthreads();
    if (isLast) {
        __threadfence();                  // acquire others' part rows
        if (tid < 128) {
            float4 acc = {0.f, 0.f, 0.f, 0.f};
            for (int r = st; r < en; ++r) {
                float4 p = ((const float4*)(part + (size_t)r * N_DIM))[tid];
                acc.x += p.x; acc.y += p.y; acc.z += p.z; acc.w += p.w;
            }
            ((float4*)(c_t + (size_t)doc * N_DIM))[tid] = acc;
        }
    }
}

extern "C" void kernel_launch(void* const* d_in, const int* in_sizes, int n_in,
                              void* d_out, int out_size, void* d_ws, size_t ws_size,
                              hipStream_t stream) {
    const float* s_t_hat        = (const float*)d_in[0];
    const float* encoder_out    = (const float*)d_in[1];
    const float* encoder_feat   = (const float*)d_in[2];
    const int*   seq_lens2      = (const int*)d_in[3];
    const float* sent_s_t_hat   = (const float*)d_in[4];
    // d_in[5] sent_enc_outputs — unused by the reference computation
    const float* sent_enc_feat  = (const float*)d_in[6];
    const float* sent_pad_mask  = (const float*)d_in[7];
    const int*   sent_lens      = (const int*)d_in[8];
    const int*   max_doc_len    = (const int*)d_in[9];
    const float* coverage       = (const float*)d_in[10];
    const float* Wd             = (const float*)d_in[11];
    const float* bd             = (const float*)d_in[12];
    const float* v_w            = (const float*)d_in[13];
    const float* Wsd            = (const float*)d_in[14];
    const float* bsd            = (const float*)d_in[15];
    const float* sv_w           = (const float*)d_in[16];

    // output layout: c_t | attn_dist_sw | coverage | sent_attn
    float* out      = (float*)d_out;
    float* o_ct     = out;
    float* o_attn   = out + B_DOC * N_DIM;
    float* o_cov    = o_attn + B_DOC * MAXDOC;
    float* o_sent   = o_cov + B_SENT * T_K;

    // workspace layout (floats)
    float* ws          = (float*)d_ws;
    float* fea_part    = ws;                                   // 32*4*512 = 65536
    float* part        = ws + 65536;                           // 1280*512 = 655360
    int*   ints        = (int*)(ws + 65536 + 655360);
    int*   doc_ids     = ints;                                 // 1280
    int*   sent_local  = ints + B_SENT;                        // 1280
    int*   doc_w_off   = ints + 2 * B_SENT;                    // 1280
    int*   sent_start  = ints + 3 * B_SENT;                    // 33
    int*   doc_wtot    = ints + 3 * B_SENT + 33;               // 32
    int*   cnt         = ints + 3 * B_SENT + 65;               // 32

    stage1_kernel<<<161, 256, 0, stream>>>(seq_lens2, sent_lens, s_t_hat,
                                           sent_s_t_hat, Wd, bd, Wsd, bsd,
                                           sent_enc_feat, sv_w, sent_pad_mask,
                                           fea_part, o_sent, doc_ids, sent_local,
                                           doc_w_off, sent_start, doc_wtot, cnt);
    fused_kernel<<<B_SENT, 256, 0, stream>>>(encoder_feat, encoder_out, fea_part,
                                             v_w, o_sent, seq_lens2, doc_ids,
                                             sent_local, doc_w_off, sent_start,
                                             doc_wtot, max_doc_len, coverage,
                                             part, o_attn, o_cov, o_ct, cnt);
}

// Round 8
// 94.108 us; speedup vs baseline: 3.1927x; 3.1927x over previous
//
#include <hip/hip_runtime.h>
#include <hip/hip_bf16.h>
#include <math.h>

// Problem constants (fixed by setup_inputs)
#define B_DOC 32
#define S_MAX 40
#define T_K 64
#define N_DIM 512
#define B_SENT (B_DOC * S_MAX)      // 1280
#define MAXDOC (S_MAX * T_K)        // 2560
#define KCHUNK 4                    // word fea GEMV k-split

__device__ __forceinline__ float fast_tanh(float x) {
    float e = __expf(2.0f * x);
    return 1.0f - 2.0f * __builtin_amdgcn_rcpf(e + 1.0f);
}

// ============ LAUNCH 1: word-fea (0..127) | prep (128) | sent attn (129..160)
__global__ __launch_bounds__(256) void stage1_kernel(
        const int* __restrict__ seq_lens2, const int* __restrict__ sent_lens,
        const float* __restrict__ s_t_hat, const float* __restrict__ sent_s_t_hat,
        const float* __restrict__ Wd, const float* __restrict__ bd,
        const float* __restrict__ Wsd, const float* __restrict__ bsd,
        const float* __restrict__ sef, const float* __restrict__ sv_w,
        const float* __restrict__ mask,
        float* __restrict__ fea_part, float* __restrict__ o_sent,
        int* __restrict__ doc_ids, int* __restrict__ sent_local,
        int* __restrict__ doc_word_off, int* __restrict__ sent_start_g,
        int* __restrict__ doc_words_total) {
    int tid = threadIdx.x;
    int blk = blockIdx.x;
    if (blk < 128) {
        // ---- word-level fea: k-split GEMV partials ----
        int c = blk & (KCHUNK - 1);
        int b = blk >> 2;
        const int KC = N_DIM / KCHUNK;   // 128
        const float* x = s_t_hat + b * N_DIM + c * KC;
        const float* W = Wd + (size_t)c * KC * N_DIM;
        float* out = fea_part + ((size_t)b * KCHUNK + c) * N_DIM;
        __shared__ float xs[128];
        if (tid < KC) xs[tid] = x[tid];
        __syncthreads();
        float a0 = 0.f, a1 = 0.f;
        if (c == 0) { a0 = bd[tid]; a1 = bd[tid + 256]; }
        #pragma unroll 8
        for (int k = 0; k < KC; ++k) {
            float xv = xs[k];
            a0 = fmaf(xv, W[k * N_DIM + tid], a0);
            a1 = fmaf(xv, W[k * N_DIM + tid + 256], a1);
        }
        out[tid] = a0;
        out[tid + 256] = a1;
    } else if (blk == 128) {
        // ---- prep: fully parallel scans ----
        __shared__ int ss[B_DOC + 1];
        __shared__ int wc[B_SENT + 1];
        __shared__ int wsum[4];
        int lane = tid & 63, w = tid >> 6;

        int ls[5];
        #pragma unroll
        for (int k = 0; k < 5; ++k) ls[k] = seq_lens2[tid * 5 + k];
        int sum = ls[0] + ls[1] + ls[2] + ls[3] + ls[4];

        int scan = sum;
        #pragma unroll
        for (int off = 1; off < 64; off <<= 1) {
            int v = __shfl_up(scan, off, 64);
            if (lane >= off) scan += v;
        }
        if (lane == 63) wsum[w] = scan;

        if (w == 0) {
            int sl = (lane < B_DOC) ? sent_lens[lane] : 0;
            int sc2 = sl;
            #pragma unroll
            for (int off = 1; off < 64; off <<= 1) {
                int v = __shfl_up(sc2, off, 64);
                if (lane >= off) sc2 += v;
            }
            if (lane < B_DOC) ss[lane + 1] = sc2;
            if (lane == 0) ss[0] = 0;
        }
        __syncthreads();

        int wbase = 0;
        for (int i = 0; i < w; ++i) wbase += wsum[i];
        int excl = wbase + scan - sum;
        #pragma unroll
        for (int k = 0; k < 5; ++k) { wc[tid * 5 + k] = excl; excl += ls[k]; }
        if (tid == 255) wc[B_SENT] = excl;
        __syncthreads();

        if (tid <= B_DOC) sent_start_g[tid] = ss[tid];
        if (tid < B_DOC) doc_words_total[tid] = wc[ss[tid + 1]] - wc[ss[tid]];

        for (int i = tid; i < B_SENT; i += 256) {
            int lo = 0, hi = B_DOC - 1;
            while (lo < hi) { int mid = (lo + hi + 1) >> 1; if (ss[mid] <= i) lo = mid; else hi = mid - 1; }
            doc_ids[i] = lo;
            sent_local[i] = i - ss[lo];
            doc_word_off[i] = wc[i] - wc[ss[lo]];
        }
    } else {
        // ---- sentence-level attention, one doc per block ----
        int doc = blk - 129;
        __shared__ __align__(16) float xs[N_DIM];
        __shared__ __align__(16) float df[N_DIM];
        __shared__ __align__(16) float vw[N_DIM];
        __shared__ float sc[S_MAX];
        xs[tid] = sent_s_t_hat[doc * N_DIM + tid];
        xs[tid + 256] = sent_s_t_hat[doc * N_DIM + tid + 256];
        vw[tid] = sv_w[tid];
        vw[tid + 256] = sv_w[tid + 256];
        __syncthreads();
        // full 512-k GEMV: sent_dec_fea = xs @ Wsd + bsd
        float a0 = bsd[tid], a1 = bsd[tid + 256];
        #pragma unroll 8
        for (int k = 0; k < N_DIM; ++k) {
            float xv = xs[k];
            a0 = fmaf(xv, Wsd[k * N_DIM + tid], a0);
            a1 = fmaf(xv, Wsd[k * N_DIM + tid + 256], a1);
        }
        df[tid] = a0;
        df[tid + 256] = a1;
        __syncthreads();
        // 40 sentence scores: 8 groups x 32 lanes, 16 dims/lane
        int g = tid >> 5, sub = tid & 31;
        const float4* df4 = (const float4*)df;
        const float4* vw4 = (const float4*)vw;
        for (int r = g; r < S_MAX; r += 8) {
            const float4* row = (const float4*)(sef + ((size_t)doc * S_MAX + r) * N_DIM);
            float acc = 0.0f;
            #pragma unroll
            for (int k = 0; k < 4; ++k) {
                int j = sub + 32 * k;
                float4 e = row[j];
                float4 d = df4[j];
                float4 v = vw4[j];
                acc = fmaf(v.x, fast_tanh(e.x + d.x), acc);
                acc = fmaf(v.y, fast_tanh(e.y + d.y), acc);
                acc = fmaf(v.z, fast_tanh(e.z + d.z), acc);
                acc = fmaf(v.w, fast_tanh(e.w + d.w), acc);
            }
            #pragma unroll
            for (int off = 16; off >= 1; off >>= 1) acc += __shfl_xor(acc, off, 32);
            if (sub == 0) sc[r] = acc;
        }
        __syncthreads();
        // masked softmax over 40 (wave 0)
        if (tid < 64) {
            bool valid = tid < S_MAX;
            float x = valid ? sc[tid] : -INFINITY;
            float m = x;
            #pragma unroll
            for (int off = 32; off >= 1; off >>= 1) m = fmaxf(m, __shfl_xor(m, off, 64));
            float mk = valid ? mask[doc * S_MAX + tid] : 0.0f;
            float e = valid ? __expf(x - m) * mk : 0.0f;
            float ssum = e;
            #pragma unroll
            for (int off = 32; off >= 1; off >>= 1) ssum += __shfl_xor(ssum, off, 64);
            if (valid) o_sent[doc * S_MAX + tid] = e / ssum;
        }
    }
}

// ============ LAUNCH 2: fused scores+softmax+context -> part ================
// 256 threads = 4 waves. Wave w, iteration i handles words t=8i+2w (half 0,
// lanes 0-31) and t+1 (half 1, lanes 32-63); 16 dims/lane. exp without max
// subtraction (|score| bounded; softmax ratio identical).
__global__ __launch_bounds__(256, 4) void fused_kernel(
        const float* __restrict__ ef, const float* __restrict__ eo,
        const float* __restrict__ fea_part, const float* __restrict__ v_w,
        const float* __restrict__ sent_attn, const int* __restrict__ seq_lens2,
        const int* __restrict__ doc_ids, const int* __restrict__ sent_local,
        const int* __restrict__ doc_word_off, const int* __restrict__ sent_start,
        const int* __restrict__ doc_words_total, const int* __restrict__ mdl,
        const float* __restrict__ cov_in,
        float* __restrict__ part, float* __restrict__ out_attn,
        float* __restrict__ out_cov) {
    int s = blockIdx.x;
    int tid = threadIdx.x;
    int w = tid >> 6, lane = tid & 63;
    int h = lane >> 5, sub = lane & 31;
    __shared__ float sc[T_K];
    __shared__ float wl[4];
    __shared__ __align__(16) float4 red[4][128];

    int doc = doc_ids[s];
    int len = seq_lens2[s];
    int maxdoc = mdl[0];

    // dec_fea (sum of 4 k-chunks) and v_w into registers at cols sub+32k
    const float4* fp4 = (const float4*)(fea_part + (size_t)doc * KCHUNK * N_DIM);
    const float4* vw4 = (const float4*)v_w;
    float4 d[4], v[4];
    #pragma unroll
    for (int k = 0; k < 4; ++k) {
        int j = sub + 32 * k;
        float4 a = fp4[j], b = fp4[128 + j], c = fp4[256 + j], e = fp4[384 + j];
        d[k].x = a.x + b.x + c.x + e.x;
        d[k].y = a.y + b.y + c.y + e.y;
        d[k].z = a.z + b.z + c.z + e.z;
        d[k].w = a.w + b.w + c.w + e.w;
        v[k] = vw4[j];
    }

    // coverage passthrough
    if (tid < T_K) out_cov[s * T_K + tid] = cov_in[s * T_K + tid];

    const float4* ef4 = (const float4*)ef + (size_t)s * T_K * 128;
    const float4* eo4 = (const float4*)eo + (size_t)s * T_K * 128;

    float l_w = 0.0f;
    float4 O[4];
    #pragma unroll
    for (int k = 0; k < 4; ++k) O[k] = (float4){0.f, 0.f, 0.f, 0.f};

    int t = 2 * w;
    float4 ea[4];
    {   // first-iteration ef prefetch (row t+h < len always: len >= 32)
        int row = t + h;
        #pragma unroll
        for (int k = 0; k < 4; ++k) ea[k] = ef4[row * 128 + sub + 32 * k];
    }
    for (; t < len; t += 8) {
        int row = t + h;
        float4 p4[4];
        #pragma unroll
        for (int k = 0; k < 4; ++k) p4[k] = eo4[row * 128 + sub + 32 * k];
        float4 eb[4];
        int tn = t + 8;
        if (tn < len) {
            int rown = tn + h;
            #pragma unroll
            for (int k = 0; k < 4; ++k) eb[k] = ef4[rown * 128 + sub + 32 * k];
        }
        float a0, a1, a2, a3;
        a0  = v[0].x * fast_tanh(ea[0].x + d[0].x);
        a1  = v[1].x * fast_tanh(ea[1].x + d[1].x);
        a2  = v[2].x * fast_tanh(ea[2].x + d[2].x);
        a3  = v[3].x * fast_tanh(ea[3].x + d[3].x);
        a0 = fmaf(v[0].y, fast_tanh(ea[0].y + d[0].y), a0);
        a1 = fmaf(v[1].y, fast_tanh(ea[1].y + d[1].y), a1);
        a2 = fmaf(v[2].y, fast_tanh(ea[2].y + d[2].y), a2);
        a3 = fmaf(v[3].y, fast_tanh(ea[3].y + d[3].y), a3);
        a0 = fmaf(v[0].z, fast_tanh(ea[0].z + d[0].z), a0);
        a1 = fmaf(v[1].z, fast_tanh(ea[1].z + d[1].z), a1);
        a2 = fmaf(v[2].z, fast_tanh(ea[2].z + d[2].z), a2);
        a3 = fmaf(v[3].z, fast_tanh(ea[3].z + d[3].z), a3);
        a0 = fmaf(v[0].w, fast_tanh(ea[0].w + d[0].w), a0);
        a1 = fmaf(v[1].w, fast_tanh(ea[1].w + d[1].w), a1);
        a2 = fmaf(v[2].w, fast_tanh(ea[2].w + d[2].w), a2);
        a3 = fmaf(v[3].w, fast_tanh(ea[3].w + d[3].w), a3);
        float acc = (a0 + a1) + (a2 + a3);
        #pragma unroll
        for (int off = 16; off >= 1; off >>= 1) acc += __shfl_xor(acc, off, 64);
        bool valid = (t + h) < len;
        if (sub == 0 && valid) sc[t + h] = acc;
        float p = valid ? __expf(acc) : 0.0f;
        l_w += p;
        #pragma unroll
        for (int k = 0; k < 4; ++k) {
            O[k].x = fmaf(p, p4[k].x, O[k].x);
            O[k].y = fmaf(p, p4[k].y, O[k].y);
            O[k].z = fmaf(p, p4[k].z, O[k].z);
            O[k].w = fmaf(p, p4[k].w, O[k].w);
        }
        #pragma unroll
        for (int k = 0; k < 4; ++k) ea[k] = eb[k];
    }

    // combine halves within wave
    l_w += __shfl_xor(l_w, 32, 64);
    #pragma unroll
    for (int k = 0; k < 4; ++k) {
        O[k].x += __shfl_xor(O[k].x, 32, 64);
        O[k].y += __shfl_xor(O[k].y, 32, 64);
        O[k].z += __shfl_xor(O[k].z, 32, 64);
        O[k].w += __shfl_xor(O[k].w, 32, 64);
    }
    if (lane == 0) wl[w] = l_w;
    if (h == 0) {
        #pragma unroll
        for (int k = 0; k < 4; ++k) red[w][sub + 32 * k] = O[k];
    }
    __syncthreads();

    float l = (wl[0] + wl[1]) + (wl[2] + wl[3]);
    float sa = sent_attn[doc * S_MAX + sent_local[s]];
    float inv = sa / l;
    if (tid < 128) {
        float4 a = red[0][tid], b = red[1][tid], c = red[2][tid], e = red[3][tid];
        float4 r = {(a.x + b.x + c.x + e.x) * inv, (a.y + b.y + c.y + e.y) * inv,
                    (a.z + b.z + c.z + e.z) * inv, (a.w + b.w + c.w + e.w) * inv};
        ((float4*)(part + (size_t)s * N_DIM))[tid] = r;
    }
    // mult_attn scatter into attn_dist_sw
    if (tid < T_K && tid < len) {
        float mu = sa * __expf(sc[tid]) / l;
        out_attn[(size_t)doc * maxdoc + doc_word_off[s] + tid] = mu;
    }
    // tail zeroing: last sentence of each doc zeroes [doc_words, maxdoc)
    if (s + 1 == sent_start[doc + 1]) {
        int dwt = doc_words_total[doc];
        for (int i = dwt + tid; i < maxdoc; i += 256)
            out_attn[(size_t)doc * maxdoc + i] = 0.0f;
    }
}

// ============ LAUNCH 3: deterministic per-doc reduction: c_t ================
__global__ __launch_bounds__(128) void reduce_kernel(
        const float* __restrict__ part, const int* __restrict__ sent_start,
        float* __restrict__ c_t) {
    int b = blockIdx.x;
    int nq = threadIdx.x;    // 128 float4 columns
    int st = sent_start[b], en = sent_start[b + 1];
    float4 acc = {0.f, 0.f, 0.f, 0.f};
    for (int s = st; s < en; ++s) {
        float4 p = ((const float4*)(part + (size_t)s * N_DIM))[nq];
        acc.x += p.x; acc.y += p.y; acc.z += p.z; acc.w += p.w;
    }
    ((float4*)(c_t + (size_t)b * N_DIM))[nq] = acc;
}

extern "C" void kernel_launch(void* const* d_in, const int* in_sizes, int n_in,
                              void* d_out, int out_size, void* d_ws, size_t ws_size,
                              hipStream_t stream) {
    const float* s_t_hat        = (const float*)d_in[0];
    const float* encoder_out    = (const float*)d_in[1];
    const float* encoder_feat   = (const float*)d_in[2];
    const int*   seq_lens2      = (const int*)d_in[3];
    const float* sent_s_t_hat   = (const float*)d_in[4];
    // d_in[5] sent_enc_outputs — unused by the reference computation
    const float* sent_enc_feat  = (const float*)d_in[6];
    const float* sent_pad_mask  = (const float*)d_in[7];
    const int*   sent_lens      = (const int*)d_in[8];
    const int*   max_doc_len    = (const int*)d_in[9];
    const float* coverage       = (const float*)d_in[10];
    const float* Wd             = (const float*)d_in[11];
    const float* bd             = (const float*)d_in[12];
    const float* v_w            = (const float*)d_in[13];
    const float* Wsd            = (const float*)d_in[14];
    const float* bsd            = (const float*)d_in[15];
    const float* sv_w           = (const float*)d_in[16];

    // output layout: c_t | attn_dist_sw | coverage | sent_attn
    float* out      = (float*)d_out;
    float* o_ct     = out;
    float* o_attn   = out + B_DOC * N_DIM;
    float* o_cov    = o_attn + B_DOC * MAXDOC;
    float* o_sent   = o_cov + B_SENT * T_K;

    // workspace layout (floats)
    float* ws          = (float*)d_ws;
    float* fea_part    = ws;                                   // 32*4*512 = 65536
    float* part        = ws + 65536;                           // 1280*512 = 655360
    int*   ints        = (int*)(ws + 65536 + 655360);
    int*   doc_ids     = ints;                                 // 1280
    int*   sent_local  = ints + B_SENT;                        // 1280
    int*   doc_w_off   = ints + 2 * B_SENT;                    // 1280
    int*   sent_start  = ints + 3 * B_SENT;                    // 33
    int*   doc_wtot    = ints + 3 * B_SENT + 33;               // 32

    stage1_kernel<<<161, 256, 0, stream>>>(seq_lens2, sent_lens, s_t_hat,
                                           sent_s_t_hat, Wd, bd, Wsd, bsd,
                                           sent_enc_feat, sv_w, sent_pad_mask,
                                           fea_part, o_sent, doc_ids, sent_local,
                                           doc_w_off, sent_start, doc_wtot);
    fused_kernel<<<B_SENT, 256, 0, stream>>>(encoder_feat, encoder_out, fea_part,
                                             v_w, o_sent, seq_lens2, doc_ids,
                                             sent_local, doc_w_off, sent_start,
                                             doc_wtot, max_doc_len, coverage,
                                             part, o_attn, o_cov);
    reduce_kernel<<<B_DOC, 128, 0, stream>>>(part, sent_start, o_ct);
}

// Round 9
// 67.065 us; speedup vs baseline: 4.4801x; 1.4032x over previous
//
#include <hip/hip_runtime.h>
#include <hip/hip_bf16.h>
#include <math.h>

// Problem constants (fixed by setup_inputs)
#define B_DOC 32
#define S_MAX 40
#define T_K 64
#define N_DIM 512
#define B_SENT (B_DOC * S_MAX)      // 1280
#define MAXDOC (S_MAX * T_K)        // 2560
#define KCHUNK 4                    // fea GEMV k-split

__device__ __forceinline__ float fast_tanh(float x) {
    float e = __expf(2.0f * x);
    return 1.0f - 2.0f * __builtin_amdgcn_rcpf(e + 1.0f);
}

// ============ LAUNCH 1: fea k-split GEMVs (0..255) | prep (256) =============
__global__ __launch_bounds__(256) void prep_fea_kernel(
        const int* __restrict__ seq_lens2, const int* __restrict__ sent_lens,
        const float* __restrict__ s_t_hat, const float* __restrict__ sent_s_t_hat,
        const float* __restrict__ Wd, const float* __restrict__ bd,
        const float* __restrict__ Wsd, const float* __restrict__ bsd,
        float* __restrict__ fea_part,
        int* __restrict__ doc_ids, int* __restrict__ sent_local,
        int* __restrict__ doc_word_off, int* __restrict__ sent_start_g,
        int* __restrict__ doc_words_total) {
    int tid = threadIdx.x;
    if (blockIdx.x == 256) {
        // ---- prep: fully parallel scans ----
        __shared__ int ss[B_DOC + 1];
        __shared__ int wc[B_SENT + 1];
        __shared__ int wsum[4];
        int lane = tid & 63, w = tid >> 6;

        int ls[5];
        #pragma unroll
        for (int k = 0; k < 5; ++k) ls[k] = seq_lens2[tid * 5 + k];
        int sum = ls[0] + ls[1] + ls[2] + ls[3] + ls[4];

        int scan = sum;
        #pragma unroll
        for (int off = 1; off < 64; off <<= 1) {
            int v = __shfl_up(scan, off, 64);
            if (lane >= off) scan += v;
        }
        if (lane == 63) wsum[w] = scan;

        if (w == 0) {
            int sl = (lane < B_DOC) ? sent_lens[lane] : 0;
            int sc2 = sl;
            #pragma unroll
            for (int off = 1; off < 64; off <<= 1) {
                int v = __shfl_up(sc2, off, 64);
                if (lane >= off) sc2 += v;
            }
            if (lane < B_DOC) ss[lane + 1] = sc2;
            if (lane == 0) ss[0] = 0;
        }
        __syncthreads();

        int wbase = 0;
        for (int i = 0; i < w; ++i) wbase += wsum[i];
        int excl = wbase + scan - sum;
        #pragma unroll
        for (int k = 0; k < 5; ++k) { wc[tid * 5 + k] = excl; excl += ls[k]; }
        if (tid == 255) wc[B_SENT] = excl;
        __syncthreads();

        if (tid <= B_DOC) sent_start_g[tid] = ss[tid];
        if (tid < B_DOC) doc_words_total[tid] = wc[ss[tid + 1]] - wc[ss[tid]];

        for (int i = tid; i < B_SENT; i += 256) {
            int lo = 0, hi = B_DOC - 1;
            while (lo < hi) { int mid = (lo + hi + 1) >> 1; if (ss[mid] <= i) lo = mid; else hi = mid - 1; }
            doc_ids[i] = lo;
            sent_local[i] = i - ss[lo];
            doc_word_off[i] = wc[i] - wc[ss[lo]];
        }
    } else {
        // ---- fea: k-split GEMV partials (both mats) ----
        int blk = blockIdx.x;
        int c = blk & (KCHUNK - 1);
        int b = (blk >> 2) & 31;
        int m = blk >> 7;
        const int KC = N_DIM / KCHUNK;   // 128
        const float* x = (m ? sent_s_t_hat : s_t_hat) + b * N_DIM + c * KC;
        const float* W = (m ? Wsd : Wd) + (size_t)c * KC * N_DIM;
        const float* bias = (m ? bsd : bd);
        float* out = fea_part + ((size_t)(m * 32 + b) * KCHUNK + c) * N_DIM;
        __shared__ float xs[128];
        if (tid < KC) xs[tid] = x[tid];
        __syncthreads();
        float a0 = 0.f, a1 = 0.f;
        if (c == 0) { a0 = bias[tid]; a1 = bias[tid + 256]; }
        #pragma unroll 8
        for (int k = 0; k < KC; ++k) {
            float xv = xs[k];
            a0 = fmaf(xv, W[k * N_DIM + tid], a0);
            a1 = fmaf(xv, W[k * N_DIM + tid + 256], a1);
        }
        out[tid] = a0;
        out[tid + 256] = a1;
    }
}

// ============ LAUNCH 2: word fused (0..1279) | sentence attn (1280..1311) ===
// Word path: scores + softmax + UNSCALED normalized w_attn + UNSCALED context
// partial (sa applied in finalize). Sent path: sentence scores + masked
// softmax -> o_sent (consumed only by finalize, so it can share this launch).
__global__ __launch_bounds__(256, 4) void fused_kernel(
        const float* __restrict__ ef, const float* __restrict__ eo,
        const float* __restrict__ sef, const float* __restrict__ fea_part,
        const float* __restrict__ v_w, const float* __restrict__ sv_w,
        const float* __restrict__ mask, const int* __restrict__ seq_lens2,
        const int* __restrict__ doc_ids, const float* __restrict__ cov_in,
        float* __restrict__ part, float* __restrict__ wn,
        float* __restrict__ out_cov, float* __restrict__ o_sent) {
    int s = blockIdx.x;
    int tid = threadIdx.x;
    int w = tid >> 6, lane = tid & 63;

    if (s >= B_SENT) {
        // ---- sentence-level attention, one doc per block ----
        int doc = s - B_SENT;
        __shared__ __align__(16) float df[N_DIM];
        __shared__ __align__(16) float vw[N_DIM];
        __shared__ float sc2[S_MAX];
        const float* fp = fea_part + (size_t)(32 + doc) * KCHUNK * N_DIM;
        for (int i = tid; i < N_DIM; i += 256) {
            df[i] = fp[i] + fp[N_DIM + i] + fp[2 * N_DIM + i] + fp[3 * N_DIM + i];
            vw[i] = sv_w[i];
        }
        __syncthreads();
        const float4* sef4 = (const float4*)(sef + (size_t)doc * S_MAX * N_DIM);
        const float4* df4 = (const float4*)df;
        const float4* vw4 = (const float4*)vw;
        for (int t = w; t < S_MAX; t += 4) {
            float acc = 0.0f;
            #pragma unroll
            for (int j = 0; j < 2; ++j) {
                int n4 = lane + 64 * j;
                float4 e = sef4[t * 128 + n4];
                float4 d = df4[n4];
                float4 v = vw4[n4];
                acc = fmaf(v.x, fast_tanh(e.x + d.x), acc);
                acc = fmaf(v.y, fast_tanh(e.y + d.y), acc);
                acc = fmaf(v.z, fast_tanh(e.z + d.z), acc);
                acc = fmaf(v.w, fast_tanh(e.w + d.w), acc);
            }
            #pragma unroll
            for (int off = 32; off >= 1; off >>= 1) acc += __shfl_xor(acc, off, 64);
            if (lane == 0) sc2[t] = acc;
        }
        __syncthreads();
        if (tid < 64) {
            bool valid = tid < S_MAX;
            float x = valid ? sc2[tid] : -INFINITY;
            float m = x;
            #pragma unroll
            for (int off = 32; off >= 1; off >>= 1) m = fmaxf(m, __shfl_xor(m, off, 64));
            float mk = valid ? mask[doc * S_MAX + tid] : 0.0f;
            float e = valid ? __expf(x - m) * mk : 0.0f;
            float ssum = e;
            #pragma unroll
            for (int off = 32; off >= 1; off >>= 1) ssum += __shfl_xor(ssum, off, 64);
            if (valid) o_sent[doc * S_MAX + tid] = e / ssum;
        }
        return;
    }

    // ---- word path: 4 waves, 2 words/wave-iteration, 16 dims/lane ----
    int h = lane >> 5, sub = lane & 31;
    __shared__ float sc[T_K];
    __shared__ float wl[4];
    __shared__ __align__(16) float4 red[4][128];

    int doc = doc_ids[s];
    int len = seq_lens2[s];

    const float4* fp4 = (const float4*)(fea_part + (size_t)doc * KCHUNK * N_DIM);
    const float4* vw4 = (const float4*)v_w;
    float4 d[4], v[4];
    #pragma unroll
    for (int k = 0; k < 4; ++k) {
        int j = sub + 32 * k;
        float4 a = fp4[j], b = fp4[128 + j], c = fp4[256 + j], e = fp4[384 + j];
        d[k].x = a.x + b.x + c.x + e.x;
        d[k].y = a.y + b.y + c.y + e.y;
        d[k].z = a.z + b.z + c.z + e.z;
        d[k].w = a.w + b.w + c.w + e.w;
        v[k] = vw4[j];
    }

    // coverage passthrough
    if (tid < T_K) out_cov[s * T_K + tid] = cov_in[s * T_K + tid];

    const float4* ef4 = (const float4*)ef + (size_t)s * T_K * 128;
    const float4* eo4 = (const float4*)eo + (size_t)s * T_K * 128;

    float l_w = 0.0f;
    float4 O[4];
    #pragma unroll
    for (int k = 0; k < 4; ++k) O[k] = (float4){0.f, 0.f, 0.f, 0.f};

    int t = 2 * w;
    float4 ea[4];
    {   // first-iteration ef prefetch (row t+h < len always: len >= 32)
        int row = t + h;
        #pragma unroll
        for (int k = 0; k < 4; ++k) ea[k] = ef4[row * 128 + sub + 32 * k];
    }
    for (; t < len; t += 8) {
        int row = t + h;
        float4 p4[4];
        #pragma unroll
        for (int k = 0; k < 4; ++k) p4[k] = eo4[row * 128 + sub + 32 * k];
        float4 eb[4];
        int tn = t + 8;
        if (tn < len) {
            int rown = tn + h;
            #pragma unroll
            for (int k = 0; k < 4; ++k) eb[k] = ef4[rown * 128 + sub + 32 * k];
        }
        float a0, a1, a2, a3;
        a0  = v[0].x * fast_tanh(ea[0].x + d[0].x);
        a1  = v[1].x * fast_tanh(ea[1].x + d[1].x);
        a2  = v[2].x * fast_tanh(ea[2].x + d[2].x);
        a3  = v[3].x * fast_tanh(ea[3].x + d[3].x);
        a0 = fmaf(v[0].y, fast_tanh(ea[0].y + d[0].y), a0);
        a1 = fmaf(v[1].y, fast_tanh(ea[1].y + d[1].y), a1);
        a2 = fmaf(v[2].y, fast_tanh(ea[2].y + d[2].y), a2);
        a3 = fmaf(v[3].y, fast_tanh(ea[3].y + d[3].y), a3);
        a0 = fmaf(v[0].z, fast_tanh(ea[0].z + d[0].z), a0);
        a1 = fmaf(v[1].z, fast_tanh(ea[1].z + d[1].z), a1);
        a2 = fmaf(v[2].z, fast_tanh(ea[2].z + d[2].z), a2);
        a3 = fmaf(v[3].z, fast_tanh(ea[3].z + d[3].z), a3);
        a0 = fmaf(v[0].w, fast_tanh(ea[0].w + d[0].w), a0);
        a1 = fmaf(v[1].w, fast_tanh(ea[1].w + d[1].w), a1);
        a2 = fmaf(v[2].w, fast_tanh(ea[2].w + d[2].w), a2);
        a3 = fmaf(v[3].w, fast_tanh(ea[3].w + d[3].w), a3);
        float acc = (a0 + a1) + (a2 + a3);
        #pragma unroll
        for (int off = 16; off >= 1; off >>= 1) acc += __shfl_xor(acc, off, 64);
        bool valid = (t + h) < len;
        if (sub == 0 && valid) sc[t + h] = acc;
        float p = valid ? __expf(acc) : 0.0f;
        l_w += p;
        #pragma unroll
        for (int k = 0; k < 4; ++k) {
            O[k].x = fmaf(p, p4[k].x, O[k].x);
            O[k].y = fmaf(p, p4[k].y, O[k].y);
            O[k].z = fmaf(p, p4[k].z, O[k].z);
            O[k].w = fmaf(p, p4[k].w, O[k].w);
        }
        #pragma unroll
        for (int k = 0; k < 4; ++k) ea[k] = eb[k];
    }

    // combine halves within wave
    l_w += __shfl_xor(l_w, 32, 64);
    #pragma unroll
    for (int k = 0; k < 4; ++k) {
        O[k].x += __shfl_xor(O[k].x, 32, 64);
        O[k].y += __shfl_xor(O[k].y, 32, 64);
        O[k].z += __shfl_xor(O[k].z, 32, 64);
        O[k].w += __shfl_xor(O[k].w, 32, 64);
    }
    if (lane == 0) wl[w] = l_w;
    if (h == 0) {
        #pragma unroll
        for (int k = 0; k < 4; ++k) red[w][sub + 32 * k] = O[k];
    }
    __syncthreads();

    float l = (wl[0] + wl[1]) + (wl[2] + wl[3]);
    float inv = 1.0f / l;                 // UNSCALED (no sa here)
    if (tid < 128) {
        float4 a = red[0][tid], b = red[1][tid], c = red[2][tid], e = red[3][tid];
        float4 r = {(a.x + b.x + c.x + e.x) * inv, (a.y + b.y + c.y + e.y) * inv,
                    (a.z + b.z + c.z + e.z) * inv, (a.w + b.w + c.w + e.w) * inv};
        ((float4*)(part + (size_t)s * N_DIM))[tid] = r;
    }
    // unscaled normalized word attention
    if (tid < T_K && tid < len) wn[s * T_K + tid] = __expf(sc[tid]) * inv;
}

// ============ LAUNCH 3: finalize — apply sa, reduce c_t, scatter attn =======
__global__ __launch_bounds__(256) void finalize_kernel(
        const float* __restrict__ part, const float* __restrict__ wn,
        const float* __restrict__ o_sent, const int* __restrict__ seq_lens2,
        const int* __restrict__ sent_start, const int* __restrict__ doc_word_off,
        const int* __restrict__ doc_words_total, const int* __restrict__ mdl,
        float* __restrict__ c_t, float* __restrict__ out_attn) {
    int doc = blockIdx.x;
    int tid = threadIdx.x;
    int maxdoc = mdl[0];
    __shared__ float sa_sh[S_MAX];
    int st = sent_start[doc], en = sent_start[doc + 1];
    int ns = en - st;
    if (tid < S_MAX) sa_sh[tid] = o_sent[doc * S_MAX + tid];
    __syncthreads();

    // c_t = sum_i sa[i] * part[st+i]  (fixed order -> deterministic)
    if (tid < 128) {
        float4 acc = {0.f, 0.f, 0.f, 0.f};
        for (int i = 0; i < ns; ++i) {
            float sa = sa_sh[i];
            float4 p = ((const float4*)(part + (size_t)(st + i) * N_DIM))[tid];
            acc.x = fmaf(sa, p.x, acc.x);
            acc.y = fmaf(sa, p.y, acc.y);
            acc.z = fmaf(sa, p.z, acc.z);
            acc.w = fmaf(sa, p.w, acc.w);
        }
        ((float4*)(c_t + (size_t)doc * N_DIM))[tid] = acc;
    }

    // attn_dist_sw scatter: 4 waves, sentence i = w, w+4, ...
    int w = tid >> 6, lane = tid & 63;
    for (int i = w; i < ns; i += 4) {
        int s = st + i;
        int len = seq_lens2[s];
        float sa = sa_sh[i];
        if (lane < len)
            out_attn[(size_t)doc * maxdoc + doc_word_off[s] + lane] =
                sa * wn[s * T_K + lane];
    }
    // tail zeroing
    int dwt = doc_words_total[doc];
    for (int i = dwt + tid; i < maxdoc; i += 256)
        out_attn[(size_t)doc * maxdoc + i] = 0.0f;
}

extern "C" void kernel_launch(void* const* d_in, const int* in_sizes, int n_in,
                              void* d_out, int out_size, void* d_ws, size_t ws_size,
                              hipStream_t stream) {
    const float* s_t_hat        = (const float*)d_in[0];
    const float* encoder_out    = (const float*)d_in[1];
    const float* encoder_feat   = (const float*)d_in[2];
    const int*   seq_lens2      = (const int*)d_in[3];
    const float* sent_s_t_hat   = (const float*)d_in[4];
    // d_in[5] sent_enc_outputs — unused by the reference computation
    const float* sent_enc_feat  = (const float*)d_in[6];
    const float* sent_pad_mask  = (const float*)d_in[7];
    const int*   sent_lens      = (const int*)d_in[8];
    const int*   max_doc_len    = (const int*)d_in[9];
    const float* coverage       = (const float*)d_in[10];
    const float* Wd             = (const float*)d_in[11];
    const float* bd             = (const float*)d_in[12];
    const float* v_w            = (const float*)d_in[13];
    const float* Wsd            = (const float*)d_in[14];
    const float* bsd            = (const float*)d_in[15];
    const float* sv_w           = (const float*)d_in[16];

    // output layout: c_t | attn_dist_sw | coverage | sent_attn
    float* out      = (float*)d_out;
    float* o_ct     = out;
    float* o_attn   = out + B_DOC * N_DIM;
    float* o_cov    = o_attn + B_DOC * MAXDOC;
    float* o_sent   = o_cov + B_SENT * T_K;

    // workspace layout (floats)
    float* ws          = (float*)d_ws;
    float* fea_part    = ws;                                   // 2*32*4*512 = 131072
    float* part        = ws + 131072;                          // 1280*512 = 655360
    float* wn          = ws + 131072 + 655360;                 // 1280*64 = 81920
    int*   ints        = (int*)(ws + 131072 + 655360 + 81920);
    int*   doc_ids     = ints;                                 // 1280
    int*   sent_local  = ints + B_SENT;                        // 1280
    int*   doc_w_off   = ints + 2 * B_SENT;                    // 1280
    int*   sent_start  = ints + 3 * B_SENT;                    // 33
    int*   doc_wtot    = ints + 3 * B_SENT + 33;               // 32

    prep_fea_kernel<<<257, 256, 0, stream>>>(seq_lens2, sent_lens, s_t_hat,
                                             sent_s_t_hat, Wd, bd, Wsd, bsd,
                                             fea_part, doc_ids, sent_local,
                                             doc_w_off, sent_start, doc_wtot);
    fused_kernel<<<B_SENT + B_DOC, 256, 0, stream>>>(encoder_feat, encoder_out,
                                                     sent_enc_feat, fea_part,
                                                     v_w, sv_w, sent_pad_mask,
                                                     seq_lens2, doc_ids, coverage,
                                                     part, wn, o_cov, o_sent);
    finalize_kernel<<<B_DOC, 256, 0, stream>>>(part, wn, o_sent, seq_lens2,
                                               sent_start, doc_w_off, doc_wtot,
                                               max_doc_len, o_ct, o_attn);
}